// Round 7
// baseline (388.471 us; speedup 1.0000x reference)
//
#include <hip/hip_runtime.h>
#include <hip/hip_bf16.h>

// Problem constants
constexpr int BATCH = 8192;   // M
constexpr int THEADS = 137;   // number of predict heads (grid.y)
constexpr int DFEA = 384;     // reduction dim of GEMM1
constexpr int KHID = 128;     // per-head hidden width
constexpr float EPS_BN = 1e-5f;
constexpr float SLOPE = 0.01f;

constexpr size_t N_F  = (size_t)BATCH * DFEA;          // 3,145,728
constexpr size_t N_W1 = (size_t)THEADS * KHID * DFEA;  // 6,733,824
constexpr size_t WS_NEED = (N_F + N_W1) * sizeof(__hip_bfloat16);
constexpr int C_F8 = (int)(N_F / 8);                   // 393,216
constexpr int C_T8 = (int)((N_F + N_W1) / 8);          // 1,234,944

typedef __attribute__((ext_vector_type(8))) short bf16x8;   // 8 bf16 = 4 VGPRs
typedef __attribute__((ext_vector_type(4))) float f32x4;

__device__ __forceinline__ short cvt_bf16(float x) {
    __hip_bfloat16 b = __float2bfloat16(x);
    return *(short*)&b;
}

__device__ __forceinline__ bf16x8 load8_cvt(const float* __restrict__ g) {
    f32x4 lo = *(const f32x4*)g;
    f32x4 hi = *(const f32x4*)(g + 4);
    bf16x8 r;
    r[0] = cvt_bf16(lo[0]); r[1] = cvt_bf16(lo[1]);
    r[2] = cvt_bf16(lo[2]); r[3] = cvt_bf16(lo[3]);
    r[4] = cvt_bf16(hi[0]); r[5] = cvt_bf16(hi[1]);
    r[6] = cvt_bf16(hi[2]); r[7] = cvt_bf16(hi[3]);
    return r;
}

// ---------------- pre-pass: fp32 -> bf16 bulk convert (f then W1, one launch) ----
__global__ __launch_bounds__(256) void cvt_pass(const float* __restrict__ f,
                                                const float* __restrict__ W1,
                                                __hip_bfloat16* __restrict__ ws) {
    int i = blockIdx.x * 256 + threadIdx.x;
    if (i < C_F8)
        *(bf16x8*)(ws + (size_t)i * 8) = load8_cvt(f + (size_t)i * 8);
    else if (i < C_T8)
        *(bf16x8*)(ws + (size_t)i * 8) = load8_cvt(W1 + ((size_t)i - C_F8) * 8);
}

// ---------------- main fused kernel v6: LDS-free, barrier-free, register-resident ---
// Same 256x128 tile / 4-wave / 64x128-per-wave geometry as v1/v5, but A AND B
// fragments load straight global->reg: the 16x16x32 fragment for row-major input
// is one contiguous 16B run per lane, so no LDS transpose staging is needed at all.
// B bytes are identical across the block's 4 waves -> L1-served after wave 0; A rows
// are L2-served (grid(32,137): bid%8 == m%8 -> per-XCD 768KB f-slice stays L2-hot).
// Frags are double-buffered in registers (set k+2 issued after the MFMAs that read
// those regs; ~1.2 iters of load-to-use slack). No __syncthreads, no ds_read, no
// inline-asm waits -- the compiler's scoreboard emits the counted vmcnt. Waves
// free-run and desynchronize, so MFMA/load phases of different waves overlap
// instead of alternating in lockstep (v1/v5's 31%-both-pipes signature).
__global__ __launch_bounds__(256, 2) void fused_heads_v6(
    const __hip_bfloat16* __restrict__ fb,     // [8192, 384] bf16
    const __hip_bfloat16* __restrict__ W1b,    // [137*128, 384] bf16
    const float* __restrict__ b1,
    const float* __restrict__ gmm,
    const float* __restrict__ bta,
    const float* __restrict__ rmean,
    const float* __restrict__ rvar,
    const float* __restrict__ W2,
    const float* __restrict__ b2,
    float* __restrict__ out)                   // [8192, 137]
{
    const int tid   = threadIdx.x;
    const int lane  = tid & 63;
    const int wm    = tid >> 6;          // wave = M-slice (0..3), rows wm*64..+64
    const int row16 = lane & 15;
    const int quad  = lane >> 4;
    const int m0 = blockIdx.x * 256;
    const int t  = blockIdx.y;
    const int n0 = t * KHID;

    // per-lane element offset within a 16-row slab (row16 rows down, quad*8 cols in)
    const int laneoff = row16 * DFEA + quad * 8;

    // wave-uniform bases forced to SGPR (readfirstlane); k-offsets stay literal imms
    const __hip_bfloat16* aB[4];
    #pragma unroll
    for (int ai = 0; ai < 4; ++ai)
        aB[ai] = fb + (size_t)__builtin_amdgcn_readfirstlane((m0 + wm * 64 + ai * 16) * DFEA)
                    + laneoff;
    const __hip_bfloat16* bB[8];
    #pragma unroll
    for (int bi = 0; bi < 8; ++bi)
        bB[bi] = W1b + (size_t)__builtin_amdgcn_readfirstlane((n0 + bi * 16) * DFEA)
                     + laneoff;

#define LOADA(dst, K)                                                 \
    { _Pragma("unroll")                                               \
      for (int ai = 0; ai < 4; ++ai)                                  \
          dst[ai] = *(const bf16x8*)(aB[ai] + (K) * 32); }

#define LOADB(dst, K)                                                 \
    { _Pragma("unroll")                                               \
      for (int bi = 0; bi < 8; ++bi)                                  \
          dst[bi] = *(const bf16x8*)(bB[bi] + (K) * 32); }

#define MFMA32(AF, BF)                                                \
    { __builtin_amdgcn_s_setprio(1);                                  \
      _Pragma("unroll")                                               \
      for (int ai = 0; ai < 4; ++ai)                                  \
          _Pragma("unroll")                                           \
          for (int bi = 0; bi < 8; ++bi)                              \
              acc[ai][bi] = __builtin_amdgcn_mfma_f32_16x16x32_bf16(  \
                  AF[ai], BF[bi], acc[ai][bi], 0, 0, 0);              \
      __builtin_amdgcn_s_setprio(0); }

    bf16x8 afa[4], bfa[8], afb[4], bfb[8];
    LOADA(afa, 0); LOADB(bfa, 0);     // set for kt=0   (12 loads in flight)
    LOADA(afb, 1); LOADB(bfb, 1);     // set for kt=1   (24 in flight)

    f32x4 acc[4][8];
    #pragma unroll
    for (int i = 0; i < 4; ++i)
        #pragma unroll
        for (int j = 0; j < 8; ++j)
            acc[i][j] = (f32x4){0.f, 0.f, 0.f, 0.f};

    // 12 K-steps, unrolled in pairs; even steps consume set-a, odd consume set-b.
    // Reload of a set sits AFTER the MFMAs that read it (program-order WAR is safe:
    // MFMA latches operands at issue), giving ~1.2 iterations of load-to-use slack.
    // The compiler's scoreboard emits the counted vmcnt before each consuming MFMA.
    #pragma unroll
    for (int kp = 0; kp < 6; ++kp) {
        MFMA32(afa, bfa);
        if (kp < 5) { LOADA(afa, 2 * kp + 2); LOADB(bfa, 2 * kp + 2); }
        MFMA32(afb, bfb);
        if (kp < 5) { LOADA(afb, 2 * kp + 3); LOADB(bfb, 2 * kp + 3); }
    }
#undef LOADA
#undef LOADB
#undef MFMA32

    // ---- fused epilogue: BN (eval) + LeakyReLU + dot with W2, all in-wave ----
    float s[8], cc[8], w2v[8];
    #pragma unroll
    for (int bi = 0; bi < 8; ++bi) {
        const int n = n0 + bi * 16 + row16;
        const float sv = gmm[n] * rsqrtf(rvar[n] + EPS_BN);
        s[bi]   = sv;
        cc[bi]  = bta[n] + (b1[n] - rmean[n]) * sv;
        w2v[bi] = W2[n];
    }

    float p[4][4];
    #pragma unroll
    for (int ai = 0; ai < 4; ++ai)
        #pragma unroll
        for (int r = 0; r < 4; ++r) {
            float a = 0.f;
            #pragma unroll
            for (int bi = 0; bi < 8; ++bi) {
                float y = acc[ai][bi][r] * s[bi] + cc[bi];
                y = (y >= 0.f) ? y : SLOPE * y;   // LeakyReLU
                a += y * w2v[bi];
            }
            p[ai][r] = a;
        }

    // reduce across the 16 column-lanes (C/D: col = lane&15); masks<16 stay in-quad
    #pragma unroll
    for (int mask = 1; mask <= 8; mask <<= 1)
        #pragma unroll
        for (int ai = 0; ai < 4; ++ai)
            #pragma unroll
            for (int r = 0; r < 4; ++r)
                p[ai][r] += __shfl_xor(p[ai][r], mask);

    if (row16 == 0) {
        const float bias = b2[t];
        #pragma unroll
        for (int ai = 0; ai < 4; ++ai)
            #pragma unroll
            for (int r = 0; r < 4; ++r) {
                const int row = m0 + wm * 64 + ai * 16 + quad * 4 + r;
                out[(size_t)row * THEADS + t] = p[ai][r] + bias;
            }
    }
}

// ---------------- fallback: direct fp32 path (unchanged) ---------------------------
__global__ __launch_bounds__(256) void fused_heads_f32(
    const float* __restrict__ f, const float* __restrict__ W1,
    const float* __restrict__ b1, const float* __restrict__ gmm,
    const float* __restrict__ bta, const float* __restrict__ rmean,
    const float* __restrict__ rvar, const float* __restrict__ W2,
    const float* __restrict__ b2, float* __restrict__ out)
{
    __shared__ __attribute__((aligned(16))) __hip_bfloat16 As[128 * 32];
    __shared__ __attribute__((aligned(16))) __hip_bfloat16 Bs[128 * 32];
    __shared__ float red[2][128];

    const int tid  = threadIdx.x;
    const int lane = tid & 63;
    const int wave = tid >> 6;
    const int wmv = wave >> 1, wn = wave & 1;
    const int m0 = blockIdx.x * 128;
    const int t  = blockIdx.y;
    const int n0 = t * KHID;

    const int li0 = tid, li1 = tid + 256;
    const int r0 = li0 >> 2, c0 = (li0 & 3) * 8;
    const int r1 = li1 >> 2, c1 = (li1 & 3) * 8;
    const float* gA0 = f  + (size_t)(m0 + r0) * DFEA + c0;
    const float* gA1 = f  + (size_t)(m0 + r1) * DFEA + c1;
    const float* gB0 = W1 + (size_t)(n0 + r0) * DFEA + c0;
    const float* gB1 = W1 + (size_t)(n0 + r1) * DFEA + c1;

    const int row16 = lane & 15, quad = lane >> 4;

    f32x4 acc[4][4];
    #pragma unroll
    for (int i = 0; i < 4; ++i)
        #pragma unroll
        for (int jx = 0; jx < 4; ++jx)
            acc[i][jx] = (f32x4){0.f, 0.f, 0.f, 0.f};

    #pragma unroll 1
    for (int kt = 0; kt < DFEA / 32; ++kt) {
        const int k0 = kt * 32;
        bf16x8 va0 = load8_cvt(gA0 + k0);
        bf16x8 va1 = load8_cvt(gA1 + k0);
        bf16x8 vb0 = load8_cvt(gB0 + k0);
        bf16x8 vb1 = load8_cvt(gB1 + k0);
        __syncthreads();
        *(bf16x8*)&As[li0 * 8] = va0;
        *(bf16x8*)&As[li1 * 8] = va1;
        *(bf16x8*)&Bs[li0 * 8] = vb0;
        *(bf16x8*)&Bs[li1 * 8] = vb1;
        __syncthreads();

        bf16x8 af[4], bfr[4];
        #pragma unroll
        for (int i = 0; i < 4; ++i)
            af[i] = *(const bf16x8*)&As[(wmv * 64 + i * 16 + row16) * 32 + quad * 8];
        #pragma unroll
        for (int i = 0; i < 4; ++i)
            bfr[i] = *(const bf16x8*)&Bs[(wn * 64 + i * 16 + row16) * 32 + quad * 8];
        #pragma unroll
        for (int ai = 0; ai < 4; ++ai)
            #pragma unroll
            for (int bi = 0; bi < 4; ++bi)
                acc[ai][bi] = __builtin_amdgcn_mfma_f32_16x16x32_bf16(
                    af[ai], bfr[bi], acc[ai][bi], 0, 0, 0);
    }

    float s[4], cc[4], w2v[4];
    #pragma unroll
    for (int bi = 0; bi < 4; ++bi) {
        const int n = n0 + wn * 64 + bi * 16 + row16;
        const float sv = gmm[n] * rsqrtf(rvar[n] + EPS_BN);
        s[bi] = sv;
        cc[bi] = bta[n] + (b1[n] - rmean[n]) * sv;
        w2v[bi] = W2[n];
    }
    float p[4][4];
    #pragma unroll
    for (int ai = 0; ai < 4; ++ai)
        #pragma unroll
        for (int r = 0; r < 4; ++r) {
            float a = 0.f;
            #pragma unroll
            for (int bi = 0; bi < 4; ++bi) {
                float y = acc[ai][bi][r] * s[bi] + cc[bi];
                y = (y >= 0.f) ? y : SLOPE * y;
                a += y * w2v[bi];
            }
            p[ai][r] = a;
        }
    #pragma unroll
    for (int mask = 1; mask <= 8; mask <<= 1)
        #pragma unroll
        for (int ai = 0; ai < 4; ++ai)
            #pragma unroll
            for (int r = 0; r < 4; ++r)
                p[ai][r] += __shfl_xor(p[ai][r], mask);
    if (row16 == 0) {
        #pragma unroll
        for (int ai = 0; ai < 4; ++ai)
            #pragma unroll
            for (int r = 0; r < 4; ++r)
                red[wn][wmv * 64 + ai * 16 + quad * 4 + r] = p[ai][r];
    }
    __syncthreads();
    if (tid < 128)
        out[(size_t)(m0 + tid) * THEADS + t] = red[0][tid] + red[1][tid] + b2[t];
}

extern "C" void kernel_launch(void* const* d_in, const int* in_sizes, int n_in,
                              void* d_out, int out_size, void* d_ws, size_t ws_size,
                              hipStream_t stream) {
    (void)in_sizes; (void)n_in; (void)out_size;
    const float* f     = (const float*)d_in[0];
    const float* W1    = (const float*)d_in[1];
    const float* b1    = (const float*)d_in[2];
    const float* gmm   = (const float*)d_in[3];
    const float* bta   = (const float*)d_in[4];
    const float* rmean = (const float*)d_in[5];
    const float* rvar  = (const float*)d_in[6];
    const float* W2    = (const float*)d_in[7];
    const float* b2    = (const float*)d_in[8];
    float* out = (float*)d_out;

    if (ws_size >= WS_NEED) {
        __hip_bfloat16* fb  = (__hip_bfloat16*)d_ws;
        __hip_bfloat16* W1b = fb + N_F;
        cvt_pass<<<(C_T8 + 255) / 256, 256, 0, stream>>>(f, W1, fb);
        dim3 grid(BATCH / 256, THEADS);
        fused_heads_v6<<<grid, 256, 0, stream>>>(fb, W1b, b1, gmm, bta, rmean, rvar, W2, b2, out);
    } else {
        dim3 grid(BATCH / 128, THEADS);
        fused_heads_f32<<<grid, 256, 0, stream>>>(f, W1, b1, gmm, bta, rmean, rvar, W2, b2, out);
    }
}

// Round 8
// 244.569 us; speedup vs baseline: 1.5884x; 1.5884x over previous
//
#include <hip/hip_runtime.h>
#include <hip/hip_bf16.h>

// Problem constants
constexpr int BATCH = 8192;   // M
constexpr int THEADS = 137;   // number of predict heads (grid.y)
constexpr int DFEA = 384;     // reduction dim of GEMM1
constexpr int KHID = 128;     // per-head hidden width
constexpr float EPS_BN = 1e-5f;
constexpr float SLOPE = 0.01f;

constexpr size_t N_F  = (size_t)BATCH * DFEA;          // 3,145,728
constexpr size_t N_W1 = (size_t)THEADS * KHID * DFEA;  // 6,733,824
constexpr size_t WS_NEED = (N_F + N_W1) * sizeof(__hip_bfloat16);
constexpr int C_F8 = (int)(N_F / 8);                   // 393,216
constexpr int C_T8 = (int)((N_F + N_W1) / 8);          // 1,234,944

typedef __attribute__((ext_vector_type(8))) short bf16x8;   // 8 bf16 = 4 VGPRs
typedef __attribute__((ext_vector_type(4))) float f32x4;

__device__ __forceinline__ short cvt_bf16(float x) {
    __hip_bfloat16 b = __float2bfloat16(x);
    return *(short*)&b;
}

__device__ __forceinline__ bf16x8 load8_cvt(const float* __restrict__ g) {
    f32x4 lo = *(const f32x4*)g;
    f32x4 hi = *(const f32x4*)(g + 4);
    bf16x8 r;
    r[0] = cvt_bf16(lo[0]); r[1] = cvt_bf16(lo[1]);
    r[2] = cvt_bf16(lo[2]); r[3] = cvt_bf16(lo[3]);
    r[4] = cvt_bf16(hi[0]); r[5] = cvt_bf16(hi[1]);
    r[6] = cvt_bf16(hi[2]); r[7] = cvt_bf16(hi[3]);
    return r;
}

__device__ __forceinline__ void gload16(const void* g, void* s) {
    // async global->LDS, 16B/lane; HW dest = readfirstlane(base) + lane*16
    __builtin_amdgcn_global_load_lds((const __attribute__((address_space(1))) void*)g,
                                     (__attribute__((address_space(3))) void*)s,
                                     16, 0, 0);
}

// ---------------- pre-pass: fp32 -> bf16 bulk convert (f then W1, one launch) ----
__global__ __launch_bounds__(256) void cvt_pass(const float* __restrict__ f,
                                                const float* __restrict__ W1,
                                                __hip_bfloat16* __restrict__ ws) {
    int i = blockIdx.x * 256 + threadIdx.x;
    if (i < C_F8)
        *(bf16x8*)(ws + (size_t)i * 8) = load8_cvt(f + (size_t)i * 8);
    else if (i < C_T8)
        *(bf16x8*)(ws + (size_t)i * 8) = load8_cvt(W1 + ((size_t)i - C_F8) * 8);
}

// ---------------- main fused kernel v7: A direct global->reg, B via LDS -------------
// v6 post-mortem: fragment-direct B multiplied VMEM ingest 4x (every wave re-pulls
// B through L1) -> VMEM-port-bound at 14% MfmaUtil. B reuse MUST go through LDS.
// A has ZERO inter-wave reuse -> its LDS round-trip (1/3 of v1's LDS traffic and
// 2/3 of its LDS writes) is pure overhead. v7 = v5's verified skeleton (256x128
// tile, 4 waves, colblock swizzle, stage-ahead + counted vmcnt, 2 barriers/step)
// with A loaded straight global->reg, double-buffered one K-step ahead.
// Per block-K-step: VMEM 24KB (same as v1), LDS ingest 48->32KB, LDS writes 24->8KB.
__global__ __launch_bounds__(256, 2) void fused_heads_v7(
    const __hip_bfloat16* __restrict__ fb,     // [8192, 384] bf16
    const __hip_bfloat16* __restrict__ W1b,    // [137*128, 384] bf16
    const float* __restrict__ b1,
    const float* __restrict__ gmm,
    const float* __restrict__ bta,
    const float* __restrict__ rmean,
    const float* __restrict__ rvar,
    const float* __restrict__ W2,
    const float* __restrict__ b2,
    float* __restrict__ out)                   // [8192, 137]
{
    __shared__ __attribute__((aligned(16))) __hip_bfloat16 Bs[2][128 * 32];  // 2x8 KB

    const int tid   = threadIdx.x;
    const int lane  = tid & 63;
    const int wm    = tid >> 6;          // wave = M-slice (0..3), rows wm*64..+64
    const int row16 = lane & 15;
    const int quad  = lane >> 4;
    const int m0 = blockIdx.x * 256;
    const int t  = blockIdx.y;
    const int n0 = t * KHID;

    const int swz = quad ^ ((row16 >> 1) & 3);   // swizzled k-colblock for B reads

    // B staging sources (v1-verified): chunk li = tid + c*256, LDS bytes li*16,
    // global row r = li>>2, colblock (li&3)^((li>>3)&3)
    const __hip_bfloat16* gB[2];
    #pragma unroll
    for (int c = 0; c < 2; ++c) {
        const int li = tid + c * 256;
        const int r = li >> 2, cb = (li & 3) ^ ((li >> 3) & 3);
        gB[c] = W1b + (size_t)(n0 + r) * DFEA + cb * 8;
    }

    // A fragment bases: lane reads row (wm*64 + ai*16 + row16), cols quad*8..+8 --
    // one contiguous 16B run per lane; wave-uniform part forced to SGPR.
    const int laneoff = row16 * DFEA + quad * 8;
    const __hip_bfloat16* aB[4];
    #pragma unroll
    for (int ai = 0; ai < 4; ++ai)
        aB[ai] = fb + (size_t)__builtin_amdgcn_readfirstlane((m0 + wm * 64 + ai * 16) * DFEA)
                    + laneoff;

#define STAGEB(BUF, K0)                                               \
    { _Pragma("unroll")                                               \
      for (int c = 0; c < 2; ++c)                                     \
          gload16(gB[c] + (K0), &Bs[BUF][(tid + c * 256) * 8]); }

#define LOADA(dst, K)                                                 \
    { _Pragma("unroll")                                               \
      for (int ai = 0; ai < 4; ++ai)                                  \
          dst[ai] = *(const bf16x8*)(aB[ai] + (K) * 32); }

    f32x4 acc[4][8];
    #pragma unroll
    for (int i = 0; i < 4; ++i)
        #pragma unroll
        for (int j = 0; j < 8; ++j)
            acc[i][j] = (f32x4){0.f, 0.f, 0.f, 0.f};

    bf16x8 afa[4], afb[4];
    STAGEB(0, 0);          // B(0) -> buf0   (2 loads in flight)
    LOADA(afa, 0);         // A(0)           (+4 = 6 in flight)

    // one K-step: stage B(kt+1), load A(kt+1), counted wait for B(kt), barrier,
    // ds_read B-frags, 32 MFMA, barrier. AFCUR/AFNEXT statically alternate (rule 20).
#define KSTEP(KT, AFCUR, AFNEXT)                                              \
    {                                                                         \
        if ((KT) < 11) {                                                      \
            STAGEB(((KT) + 1) & 1, ((KT) + 1) * 32);                          \
            LOADA(AFNEXT, (KT) + 1);                                          \
            asm volatile("s_waitcnt vmcnt(6)" ::: "memory");                  \
        } else {                                                              \
            asm volatile("s_waitcnt vmcnt(0)" ::: "memory");                  \
        }                                                                     \
        __builtin_amdgcn_s_barrier();                                         \
        __builtin_amdgcn_sched_barrier(0);                                    \
        bf16x8 bfr[8];                                                        \
        _Pragma("unroll")                                                     \
        for (int bi = 0; bi < 8; ++bi)                                        \
            bfr[bi] = *(const bf16x8*)&Bs[(KT) & 1][(bi * 16 + row16) * 32 + swz * 8]; \
        __builtin_amdgcn_s_setprio(1);                                        \
        _Pragma("unroll")                                                     \
        for (int ai = 0; ai < 4; ++ai)                                        \
            _Pragma("unroll")                                                 \
            for (int bi = 0; bi < 8; ++bi)                                    \
                acc[ai][bi] = __builtin_amdgcn_mfma_f32_16x16x32_bf16(        \
                    AFCUR[ai], bfr[bi], acc[ai][bi], 0, 0, 0);                \
        __builtin_amdgcn_s_setprio(0);                                        \
        __builtin_amdgcn_s_barrier();                                         \
    }

    #pragma unroll
    for (int kp = 0; kp < 6; ++kp) {
        KSTEP(2 * kp,     afa, afb)
        KSTEP(2 * kp + 1, afb, afa)
    }
#undef KSTEP
#undef STAGEB
#undef LOADA

    // ---- fused epilogue: BN (eval) + LeakyReLU + dot with W2, all in-wave ----
    float s[8], cc[8], w2v[8];
    #pragma unroll
    for (int bi = 0; bi < 8; ++bi) {
        const int n = n0 + bi * 16 + row16;
        const float sv = gmm[n] * rsqrtf(rvar[n] + EPS_BN);
        s[bi]   = sv;
        cc[bi]  = bta[n] + (b1[n] - rmean[n]) * sv;
        w2v[bi] = W2[n];
    }

    float p[4][4];
    #pragma unroll
    for (int ai = 0; ai < 4; ++ai)
        #pragma unroll
        for (int r = 0; r < 4; ++r) {
            float a = 0.f;
            #pragma unroll
            for (int bi = 0; bi < 8; ++bi) {
                float y = acc[ai][bi][r] * s[bi] + cc[bi];
                y = (y >= 0.f) ? y : SLOPE * y;   // LeakyReLU
                a += y * w2v[bi];
            }
            p[ai][r] = a;
        }

    // reduce across the 16 column-lanes (C/D: col = lane&15); masks<16 stay in-quad
    #pragma unroll
    for (int mask = 1; mask <= 8; mask <<= 1)
        #pragma unroll
        for (int ai = 0; ai < 4; ++ai)
            #pragma unroll
            for (int r = 0; r < 4; ++r)
                p[ai][r] += __shfl_xor(p[ai][r], mask);

    if (row16 == 0) {
        const float bias = b2[t];
        #pragma unroll
        for (int ai = 0; ai < 4; ++ai)
            #pragma unroll
            for (int r = 0; r < 4; ++r) {
                const int row = m0 + wm * 64 + ai * 16 + quad * 4 + r;
                out[(size_t)row * THEADS + t] = p[ai][r] + bias;
            }
    }
}

// ---------------- fallback: direct fp32 path (unchanged) ---------------------------
__global__ __launch_bounds__(256) void fused_heads_f32(
    const float* __restrict__ f, const float* __restrict__ W1,
    const float* __restrict__ b1, const float* __restrict__ gmm,
    const float* __restrict__ bta, const float* __restrict__ rmean,
    const float* __restrict__ rvar, const float* __restrict__ W2,
    const float* __restrict__ b2, float* __restrict__ out)
{
    __shared__ __attribute__((aligned(16))) __hip_bfloat16 As[128 * 32];
    __shared__ __attribute__((aligned(16))) __hip_bfloat16 Bs[128 * 32];
    __shared__ float red[2][128];

    const int tid  = threadIdx.x;
    const int lane = tid & 63;
    const int wave = tid >> 6;
    const int wmv = wave >> 1, wn = wave & 1;
    const int m0 = blockIdx.x * 128;
    const int t  = blockIdx.y;
    const int n0 = t * KHID;

    const int li0 = tid, li1 = tid + 256;
    const int r0 = li0 >> 2, c0 = (li0 & 3) * 8;
    const int r1 = li1 >> 2, c1 = (li1 & 3) * 8;
    const float* gA0 = f  + (size_t)(m0 + r0) * DFEA + c0;
    const float* gA1 = f  + (size_t)(m0 + r1) * DFEA + c1;
    const float* gB0 = W1 + (size_t)(n0 + r0) * DFEA + c0;
    const float* gB1 = W1 + (size_t)(n0 + r1) * DFEA + c1;

    const int row16 = lane & 15, quad = lane >> 4;

    f32x4 acc[4][4];
    #pragma unroll
    for (int i = 0; i < 4; ++i)
        #pragma unroll
        for (int jx = 0; jx < 4; ++jx)
            acc[i][jx] = (f32x4){0.f, 0.f, 0.f, 0.f};

    #pragma unroll 1
    for (int kt = 0; kt < DFEA / 32; ++kt) {
        const int k0 = kt * 32;
        bf16x8 va0 = load8_cvt(gA0 + k0);
        bf16x8 va1 = load8_cvt(gA1 + k0);
        bf16x8 vb0 = load8_cvt(gB0 + k0);
        bf16x8 vb1 = load8_cvt(gB1 + k0);
        __syncthreads();
        *(bf16x8*)&As[li0 * 8] = va0;
        *(bf16x8*)&As[li1 * 8] = va1;
        *(bf16x8*)&Bs[li0 * 8] = vb0;
        *(bf16x8*)&Bs[li1 * 8] = vb1;
        __syncthreads();

        bf16x8 af[4], bfr[4];
        #pragma unroll
        for (int i = 0; i < 4; ++i)
            af[i] = *(const bf16x8*)&As[(wmv * 64 + i * 16 + row16) * 32 + quad * 8];
        #pragma unroll
        for (int i = 0; i < 4; ++i)
            bfr[i] = *(const bf16x8*)&Bs[(wn * 64 + i * 16 + row16) * 32 + quad * 8];
        #pragma unroll
        for (int ai = 0; ai < 4; ++ai)
            #pragma unroll
            for (int bi = 0; bi < 4; ++bi)
                acc[ai][bi] = __builtin_amdgcn_mfma_f32_16x16x32_bf16(
                    af[ai], bfr[bi], acc[ai][bi], 0, 0, 0);
    }

    float s[4], cc[4], w2v[4];
    #pragma unroll
    for (int bi = 0; bi < 4; ++bi) {
        const int n = n0 + wn * 64 + bi * 16 + row16;
        const float sv = gmm[n] * rsqrtf(rvar[n] + EPS_BN);
        s[bi] = sv;
        cc[bi] = bta[n] + (b1[n] - rmean[n]) * sv;
        w2v[bi] = W2[n];
    }
    float p[4][4];
    #pragma unroll
    for (int ai = 0; ai < 4; ++ai)
        #pragma unroll
        for (int r = 0; r < 4; ++r) {
            float a = 0.f;
            #pragma unroll
            for (int bi = 0; bi < 4; ++bi) {
                float y = acc[ai][bi][r] * s[bi] + cc[bi];
                y = (y >= 0.f) ? y : SLOPE * y;
                a += y * w2v[bi];
            }
            p[ai][r] = a;
        }
    #pragma unroll
    for (int mask = 1; mask <= 8; mask <<= 1)
        #pragma unroll
        for (int ai = 0; ai < 4; ++ai)
            #pragma unroll
            for (int r = 0; r < 4; ++r)
                p[ai][r] += __shfl_xor(p[ai][r], mask);
    if (row16 == 0) {
        #pragma unroll
        for (int ai = 0; ai < 4; ++ai)
            #pragma unroll
            for (int r = 0; r < 4; ++r)
                red[wn][wmv * 64 + ai * 16 + quad * 4 + r] = p[ai][r];
    }
    __syncthreads();
    if (tid < 128)
        out[(size_t)(m0 + tid) * THEADS + t] = red[0][tid] + red[1][tid] + b2[t];
}

extern "C" void kernel_launch(void* const* d_in, const int* in_sizes, int n_in,
                              void* d_out, int out_size, void* d_ws, size_t ws_size,
                              hipStream_t stream) {
    (void)in_sizes; (void)n_in; (void)out_size;
    const float* f     = (const float*)d_in[0];
    const float* W1    = (const float*)d_in[1];
    const float* b1    = (const float*)d_in[2];
    const float* gmm   = (const float*)d_in[3];
    const float* bta   = (const float*)d_in[4];
    const float* rmean = (const float*)d_in[5];
    const float* rvar  = (const float*)d_in[6];
    const float* W2    = (const float*)d_in[7];
    const float* b2    = (const float*)d_in[8];
    float* out = (float*)d_out;

    if (ws_size >= WS_NEED) {
        __hip_bfloat16* fb  = (__hip_bfloat16*)d_ws;
        __hip_bfloat16* W1b = fb + N_F;
        cvt_pass<<<(C_T8 + 255) / 256, 256, 0, stream>>>(f, W1, fb);
        dim3 grid(BATCH / 256, THEADS);
        fused_heads_v7<<<grid, 256, 0, stream>>>(fb, W1b, b1, gmm, bta, rmean, rvar, W2, b2, out);
    } else {
        dim3 grid(BATCH / 128, THEADS);
        fused_heads_f32<<<grid, 256, 0, stream>>>(f, W1, b1, gmm, bta, rmean, rvar, W2, b2, out);
    }
}

// Round 9
// 221.511 us; speedup vs baseline: 1.7537x; 1.1041x over previous
//
#include <hip/hip_runtime.h>
#include <hip/hip_bf16.h>

// Problem constants
constexpr int BATCH = 8192;   // M
constexpr int THEADS = 137;   // number of predict heads (grid.y)
constexpr int DFEA = 384;     // reduction dim of GEMM1
constexpr int KHID = 128;     // per-head hidden width
constexpr float EPS_BN = 1e-5f;
constexpr float SLOPE = 0.01f;

constexpr size_t N_F  = (size_t)BATCH * DFEA;          // 3,145,728
constexpr size_t N_W1 = (size_t)THEADS * KHID * DFEA;  // 6,733,824
constexpr size_t WS_NEED = (N_F + N_W1) * sizeof(__hip_bfloat16);
constexpr int C_F8 = (int)(N_F / 8);                   // 393,216
constexpr int C_T8 = (int)((N_F + N_W1) / 8);          // 1,234,944

typedef __attribute__((ext_vector_type(8))) short bf16x8;   // 8 bf16 = 4 VGPRs
typedef __attribute__((ext_vector_type(4))) float f32x4;

__device__ __forceinline__ short cvt_bf16(float x) {
    __hip_bfloat16 b = __float2bfloat16(x);
    return *(short*)&b;
}

__device__ __forceinline__ bf16x8 load8_cvt(const float* __restrict__ g) {
    f32x4 lo = *(const f32x4*)g;
    f32x4 hi = *(const f32x4*)(g + 4);
    bf16x8 r;
    r[0] = cvt_bf16(lo[0]); r[1] = cvt_bf16(lo[1]);
    r[2] = cvt_bf16(lo[2]); r[3] = cvt_bf16(lo[3]);
    r[4] = cvt_bf16(hi[0]); r[5] = cvt_bf16(hi[1]);
    r[6] = cvt_bf16(hi[2]); r[7] = cvt_bf16(hi[3]);
    return r;
}

__device__ __forceinline__ void gload16(const void* g, void* s) {
    // async global->LDS, 16B/lane; HW dest = readfirstlane(base) + lane*16
    __builtin_amdgcn_global_load_lds((const __attribute__((address_space(1))) void*)g,
                                     (__attribute__((address_space(3))) void*)s,
                                     16, 0, 0);
}

// ---------------- pre-pass: fp32 -> bf16 bulk convert (f then W1, one launch) ----
__global__ __launch_bounds__(256) void cvt_pass(const float* __restrict__ f,
                                                const float* __restrict__ W1,
                                                __hip_bfloat16* __restrict__ ws) {
    int i = blockIdx.x * 256 + threadIdx.x;
    if (i < C_F8)
        *(bf16x8*)(ws + (size_t)i * 8) = load8_cvt(f + (size_t)i * 8);
    else if (i < C_T8)
        *(bf16x8*)(ws + (size_t)i * 8) = load8_cvt(W1 + ((size_t)i - C_F8) * 8);
}

// ---------------- main fused kernel v8: triple-buffer, ONE barrier per K-step -------
// Ledger: v1=150us/31% MfmaUtil, v5(dbuf+vmcnt)=157/31 (null), v7(A-reg)=172/27,
// v6(all-reg)=316/14. Diagnosis: 2 blocks/CU (AGPR-capped) in barrier lockstep ->
// per-step phases (stage-wait, 12 ds_reads, 32 MFMA, 2 barriers) serialize.
// v8 deletes the WAR barrier via TRIPLE buffering: stage issued at iter kt targets
// buf (kt+2)%3 whose readers finished at iter kt-1 -- the single per-iter barrier
// transitively orders them. Per K-step: vmcnt(6) -> s_barrier -> issue stage(kt+2)
// -> ds_read buf(kt%3) -> MFMA. Stage depth = 2 iterations of latency slack;
// barriers 24->12 per block; waves free-run (de-phase) between barriers.
// vmcnt: 6 loads/thread/stage, steady-state 12 in flight -> vmcnt(6) = stage(kt) done.
__global__ __launch_bounds__(256, 2) void fused_heads_v8(
    const __hip_bfloat16* __restrict__ fb,     // [8192, 384] bf16
    const __hip_bfloat16* __restrict__ W1b,    // [137*128, 384] bf16
    const float* __restrict__ b1,
    const float* __restrict__ gmm,
    const float* __restrict__ bta,
    const float* __restrict__ rmean,
    const float* __restrict__ rvar,
    const float* __restrict__ W2,
    const float* __restrict__ b2,
    float* __restrict__ out)                   // [8192, 137]
{
    __shared__ __attribute__((aligned(16))) __hip_bfloat16 As[3][256 * 32];  // 3x16 KB
    __shared__ __attribute__((aligned(16))) __hip_bfloat16 Bs[3][128 * 32];  // 3x 8 KB

    const int tid  = threadIdx.x;
    const int lane = tid & 63;
    const int wm   = tid >> 6;          // wave = M-slice (0..3), rows wm*64..+64
    const int m0 = blockIdx.x * 256;
    const int t  = blockIdx.y;
    const int n0 = t * KHID;

    const int row16 = lane & 15;
    const int quad  = lane >> 4;
    const int swz   = quad ^ ((row16 >> 1) & 3);   // swizzled k-colblock for reads

    // staging sources (v1-verified): chunk li = tid + c*256, LDS bytes li*16,
    // global row r = li>>2, colblock (li&3)^((li>>3)&3)
    const __hip_bfloat16* gA[4];
    const __hip_bfloat16* gB[2];
    #pragma unroll
    for (int c = 0; c < 4; ++c) {
        const int li = tid + c * 256;
        const int r = li >> 2, cb = (li & 3) ^ ((li >> 3) & 3);
        gA[c] = fb + (size_t)(m0 + r) * DFEA + cb * 8;
    }
    #pragma unroll
    for (int c = 0; c < 2; ++c) {
        const int li = tid + c * 256;
        const int r = li >> 2, cb = (li & 3) ^ ((li >> 3) & 3);
        gB[c] = W1b + (size_t)(n0 + r) * DFEA + cb * 8;
    }

    f32x4 acc[4][8];
    #pragma unroll
    for (int i = 0; i < 4; ++i)
        #pragma unroll
        for (int j = 0; j < 8; ++j)
            acc[i][j] = (f32x4){0.f, 0.f, 0.f, 0.f};

#define STAGE(BUF, K0)                                                      \
    {                                                                       \
        _Pragma("unroll")                                                   \
        for (int c = 0; c < 4; ++c)                                         \
            gload16(gA[c] + (K0), &As[BUF][(tid + c * 256) * 8]);           \
        _Pragma("unroll")                                                   \
        for (int c = 0; c < 2; ++c)                                         \
            gload16(gB[c] + (K0), &Bs[BUF][(tid + c * 256) * 8]);           \
    }

    STAGE(0, 0);       // stage(0) -> buf0   (6 loads/thread in flight)
    STAGE(1, 32);      // stage(1) -> buf1   (12 in flight)

    // One K-step. KT/CUR/STG are literals after unrolling (static LDS indexing).
#define KSTEP(KT, CUR, STG)                                                   \
    {                                                                         \
        if ((KT) < 11) { asm volatile("s_waitcnt vmcnt(6)" ::: "memory"); }   \
        else           { asm volatile("s_waitcnt vmcnt(0)" ::: "memory"); }   \
        __builtin_amdgcn_s_barrier();          /* stage(KT) valid for all */  \
        __builtin_amdgcn_sched_barrier(0);     /* no ds_read hoists above */  \
        if ((KT) < 10) STAGE(STG, ((KT) + 2) * 32);                           \
        bf16x8 af[4], bfr[8];                                                 \
        _Pragma("unroll")                                                     \
        for (int ai = 0; ai < 4; ++ai)                                        \
            af[ai] = *(const bf16x8*)&As[CUR][(wm * 64 + ai * 16 + row16) * 32 + swz * 8]; \
        _Pragma("unroll")                                                     \
        for (int bi = 0; bi < 8; ++bi)                                        \
            bfr[bi] = *(const bf16x8*)&Bs[CUR][(bi * 16 + row16) * 32 + swz * 8]; \
        __builtin_amdgcn_s_setprio(1);                                        \
        _Pragma("unroll")                                                     \
        for (int ai = 0; ai < 4; ++ai)                                        \
            _Pragma("unroll")                                                 \
            for (int bi = 0; bi < 8; ++bi)                                    \
                acc[ai][bi] = __builtin_amdgcn_mfma_f32_16x16x32_bf16(        \
                    af[ai], bfr[bi], acc[ai][bi], 0, 0, 0);                   \
        __builtin_amdgcn_s_setprio(0);                                        \
    }

    #pragma unroll
    for (int kp = 0; kp < 4; ++kp) {
        KSTEP(3 * kp,     0, 2)
        KSTEP(3 * kp + 1, 1, 0)
        KSTEP(3 * kp + 2, 2, 1)
    }
#undef KSTEP
#undef STAGE

    // ---- fused epilogue: BN (eval) + LeakyReLU + dot with W2, all in-wave ----
    float s[8], cc[8], w2v[8];
    #pragma unroll
    for (int bi = 0; bi < 8; ++bi) {
        const int n = n0 + bi * 16 + row16;
        const float sv = gmm[n] * rsqrtf(rvar[n] + EPS_BN);
        s[bi]   = sv;
        cc[bi]  = bta[n] + (b1[n] - rmean[n]) * sv;
        w2v[bi] = W2[n];
    }

    float p[4][4];
    #pragma unroll
    for (int ai = 0; ai < 4; ++ai)
        #pragma unroll
        for (int r = 0; r < 4; ++r) {
            float a = 0.f;
            #pragma unroll
            for (int bi = 0; bi < 8; ++bi) {
                float y = acc[ai][bi][r] * s[bi] + cc[bi];
                y = (y >= 0.f) ? y : SLOPE * y;   // LeakyReLU
                a += y * w2v[bi];
            }
            p[ai][r] = a;
        }

    // reduce across the 16 column-lanes (C/D: col = lane&15); masks<16 stay in-quad
    #pragma unroll
    for (int mask = 1; mask <= 8; mask <<= 1)
        #pragma unroll
        for (int ai = 0; ai < 4; ++ai)
            #pragma unroll
            for (int r = 0; r < 4; ++r)
                p[ai][r] += __shfl_xor(p[ai][r], mask);

    if (row16 == 0) {
        const float bias = b2[t];
        #pragma unroll
        for (int ai = 0; ai < 4; ++ai)
            #pragma unroll
            for (int r = 0; r < 4; ++r) {
                const int row = m0 + wm * 64 + ai * 16 + quad * 4 + r;
                out[(size_t)row * THEADS + t] = p[ai][r] + bias;
            }
    }
}

// ---------------- fallback: direct fp32 path (unchanged) ---------------------------
__global__ __launch_bounds__(256) void fused_heads_f32(
    const float* __restrict__ f, const float* __restrict__ W1,
    const float* __restrict__ b1, const float* __restrict__ gmm,
    const float* __restrict__ bta, const float* __restrict__ rmean,
    const float* __restrict__ rvar, const float* __restrict__ W2,
    const float* __restrict__ b2, float* __restrict__ out)
{
    __shared__ __attribute__((aligned(16))) __hip_bfloat16 As[128 * 32];
    __shared__ __attribute__((aligned(16))) __hip_bfloat16 Bs[128 * 32];
    __shared__ float red[2][128];

    const int tid  = threadIdx.x;
    const int lane = tid & 63;
    const int wave = tid >> 6;
    const int wmv = wave >> 1, wn = wave & 1;
    const int m0 = blockIdx.x * 128;
    const int t  = blockIdx.y;
    const int n0 = t * KHID;

    const int li0 = tid, li1 = tid + 256;
    const int r0 = li0 >> 2, c0 = (li0 & 3) * 8;
    const int r1 = li1 >> 2, c1 = (li1 & 3) * 8;
    const float* gA0 = f  + (size_t)(m0 + r0) * DFEA + c0;
    const float* gA1 = f  + (size_t)(m0 + r1) * DFEA + c1;
    const float* gB0 = W1 + (size_t)(n0 + r0) * DFEA + c0;
    const float* gB1 = W1 + (size_t)(n0 + r1) * DFEA + c1;

    const int row16 = lane & 15, quad = lane >> 4;

    f32x4 acc[4][4];
    #pragma unroll
    for (int i = 0; i < 4; ++i)
        #pragma unroll
        for (int jx = 0; jx < 4; ++jx)
            acc[i][jx] = (f32x4){0.f, 0.f, 0.f, 0.f};

    #pragma unroll 1
    for (int kt = 0; kt < DFEA / 32; ++kt) {
        const int k0 = kt * 32;
        bf16x8 va0 = load8_cvt(gA0 + k0);
        bf16x8 va1 = load8_cvt(gA1 + k0);
        bf16x8 vb0 = load8_cvt(gB0 + k0);
        bf16x8 vb1 = load8_cvt(gB1 + k0);
        __syncthreads();
        *(bf16x8*)&As[li0 * 8] = va0;
        *(bf16x8*)&As[li1 * 8] = va1;
        *(bf16x8*)&Bs[li0 * 8] = vb0;
        *(bf16x8*)&Bs[li1 * 8] = vb1;
        __syncthreads();

        bf16x8 af[4], bfr[4];
        #pragma unroll
        for (int i = 0; i < 4; ++i)
            af[i] = *(const bf16x8*)&As[(wmv * 64 + i * 16 + row16) * 32 + quad * 8];
        #pragma unroll
        for (int i = 0; i < 4; ++i)
            bfr[i] = *(const bf16x8*)&Bs[(wn * 64 + i * 16 + row16) * 32 + quad * 8];
        #pragma unroll
        for (int ai = 0; ai < 4; ++ai)
            #pragma unroll
            for (int bi = 0; bi < 4; ++bi)
                acc[ai][bi] = __builtin_amdgcn_mfma_f32_16x16x32_bf16(
                    af[ai], bfr[bi], acc[ai][bi], 0, 0, 0);
    }

    float s[4], cc[4], w2v[4];
    #pragma unroll
    for (int bi = 0; bi < 4; ++bi) {
        const int n = n0 + wn * 64 + bi * 16 + row16;
        const float sv = gmm[n] * rsqrtf(rvar[n] + EPS_BN);
        s[bi] = sv;
        cc[bi] = bta[n] + (b1[n] - rmean[n]) * sv;
        w2v[bi] = W2[n];
    }
    float p[4][4];
    #pragma unroll
    for (int ai = 0; ai < 4; ++ai)
        #pragma unroll
        for (int r = 0; r < 4; ++r) {
            float a = 0.f;
            #pragma unroll
            for (int bi = 0; bi < 4; ++bi) {
                float y = acc[ai][bi][r] * s[bi] + cc[bi];
                y = (y >= 0.f) ? y : SLOPE * y;
                a += y * w2v[bi];
            }
            p[ai][r] = a;
        }
    #pragma unroll
    for (int mask = 1; mask <= 8; mask <<= 1)
        #pragma unroll
        for (int ai = 0; ai < 4; ++ai)
            #pragma unroll
            for (int r = 0; r < 4; ++r)
                p[ai][r] += __shfl_xor(p[ai][r], mask);
    if (row16 == 0) {
        #pragma unroll
        for (int ai = 0; ai < 4; ++ai)
            #pragma unroll
            for (int r = 0; r < 4; ++r)
                red[wn][wmv * 64 + ai * 16 + quad * 4 + r] = p[ai][r];
    }
    __syncthreads();
    if (tid < 128)
        out[(size_t)(m0 + tid) * THEADS + t] = red[0][tid] + red[1][tid] + b2[t];
}

extern "C" void kernel_launch(void* const* d_in, const int* in_sizes, int n_in,
                              void* d_out, int out_size, void* d_ws, size_t ws_size,
                              hipStream_t stream) {
    (void)in_sizes; (void)n_in; (void)out_size;
    const float* f     = (const float*)d_in[0];
    const float* W1    = (const float*)d_in[1];
    const float* b1    = (const float*)d_in[2];
    const float* gmm   = (const float*)d_in[3];
    const float* bta   = (const float*)d_in[4];
    const float* rmean = (const float*)d_in[5];
    const float* rvar  = (const float*)d_in[6];
    const float* W2    = (const float*)d_in[7];
    const float* b2    = (const float*)d_in[8];
    float* out = (float*)d_out;

    if (ws_size >= WS_NEED) {
        __hip_bfloat16* fb  = (__hip_bfloat16*)d_ws;
        __hip_bfloat16* W1b = fb + N_F;
        cvt_pass<<<(C_T8 + 255) / 256, 256, 0, stream>>>(f, W1, fb);
        dim3 grid(BATCH / 256, THEADS);
        fused_heads_v8<<<grid, 256, 0, stream>>>(fb, W1b, b1, gmm, bta, rmean, rvar, W2, b2, out);
    } else {
        dim3 grid(BATCH / 128, THEADS);
        fused_heads_f32<<<grid, 256, 0, stream>>>(f, W1, b1, gmm, bta, rmean, rvar, W2, b2, out);
    }
}